// Round 6
// baseline (969.255 us; speedup 1.0000x reference)
//
#include <hip/hip_runtime.h>
#include <hip/hip_bf16.h>

constexpr int NN = 50000;       // nodes
constexpr int NE = 800000;      // edges per graph
constexpr int NP = 50176;       // padded per-graph node stride
constexpr int RP = 50240;       // row-offset stride (>= NN+1)

// ---------------- CSR / norm build ----------------
// combo[node]: bits 44..63 = edge count, bits 0..43 = sum(w) in 2^-32 fixed point.
// One 64-bit atomic per edge; returned old count field = edge's rank in its dst row.

__global__ __launch_bounds__(256) void k_count(
    const int* __restrict__ e0, const int* __restrict__ e1, const int* __restrict__ e2,
    const float* __restrict__ w1, const float* __restrict__ w2,
    unsigned long long* __restrict__ combo, unsigned short* __restrict__ rank) {
    int g = blockIdx.y;
    int e = blockIdx.x * 256 + threadIdx.x;
    if (e >= NE) return;
    const int* ep = (g == 0) ? e0 : (g == 1) ? e1 : e2;
    float w = (g == 0) ? 1.0f : (g == 1) ? w1[e] : w2[e];
    int dst = ep[NE + e];
    unsigned long long wfix = (unsigned long long)llrint((double)w * 4294967296.0);
    unsigned long long old = atomicAdd(&combo[g * NP + dst], (1ULL << 44) | wfix);
    rank[(size_t)g * NE + e] = (unsigned short)(old >> 44);
}

__global__ __launch_bounds__(256) void k_dinv(const unsigned long long* __restrict__ combo,
                                              float* __restrict__ dinv) {
    int i = blockIdx.x * 256 + threadIdx.x;
    if (i >= 3 * NP) return;
    unsigned long long v = combo[i];
    double d = (double)(v & ((1ULL << 44) - 1)) * (1.0 / 4294967296.0) + 1.0;  // + self-loop
    dinv[i] = (float)(1.0 / sqrt(d));   // d >= 1 always
}

// one workgroup per graph: chunked sequential sums + Hillis-Steele scan of partials
__global__ __launch_bounds__(1024) void k_scan(const unsigned long long* __restrict__ combo,
                                               int* __restrict__ roff) {
    int g = blockIdx.x;
    const unsigned long long* c = combo + g * NP;
    int* r = roff + g * RP;
    int t = threadIdx.x;
    constexpr int CH = (NN + 1023) / 1024;  // 49
    int lo = t * CH;
    int hi = lo + CH < NN ? lo + CH : NN;
    int s = 0;
    for (int i = lo; i < hi; ++i) s += (int)(c[i] >> 44);
    __shared__ int part[1024];
    part[t] = s;
    __syncthreads();
    for (int off = 1; off < 1024; off <<= 1) {
        int v = (t >= off) ? part[t - off] : 0;
        __syncthreads();
        part[t] += v;
        __syncthreads();
    }
    int run = part[t] - s;  // exclusive base for this chunk
    for (int i = lo; i < hi; ++i) { r[i] = run; run += (int)(c[i] >> 44); }
    if (t == 1023) r[NN] = part[1023];
}

__global__ __launch_bounds__(256) void k_fill(
    const int* __restrict__ e0, const int* __restrict__ e1, const int* __restrict__ e2,
    const float* __restrict__ w1, const float* __restrict__ w2,
    const float* __restrict__ dinv, const int* __restrict__ roff,
    const unsigned short* __restrict__ rank, int2* __restrict__ csr) {
    int g = blockIdx.y;
    int e = blockIdx.x * 256 + threadIdx.x;
    if (e >= NE) return;
    const int* ep = (g == 0) ? e0 : (g == 1) ? e1 : e2;
    float w = (g == 0) ? 1.0f : (g == 1) ? w1[e] : w2[e];
    int src = ep[e];
    int dst = ep[NE + e];
    float nrm = dinv[g * NP + src] * w * dinv[g * NP + dst];
    int pos = roff[g * RP + dst] + (int)rank[(size_t)g * NE + e];
    csr[(size_t)g * NE + pos] = make_int2(src, __float_as_int(nrm));
}

// ---------------- fp32 tiled GEMM: H[N,M] = X[N,K] @ W[M,K]^T ----------------

template <int K, int M>
__global__ __launch_bounds__(256) void k_gemm(const float* __restrict__ X,
                                              const float* __restrict__ W,
                                              float* __restrict__ H) {
    constexpr int BM = 64, KC = 32;
    constexpr int CG = M / 4;      // col groups (32 or 16)
    constexpr int RG = 256 / CG;   // row groups (8 or 16)
    constexpr int RPT = BM / RG;   // rows per thread (8 or 4)
    __shared__ __align__(16) float xs[KC][68];      // [k][row], +4 pad
    __shared__ __align__(16) float ws[KC][M + 4];   // [k][m]
    int t = threadIdx.x;
    int row0 = blockIdx.x * BM;
    int col4 = t % CG;
    int rbase = (t / CG) * RPT;
    float acc[RPT][4];
#pragma unroll
    for (int i = 0; i < RPT; ++i)
#pragma unroll
        for (int j = 0; j < 4; ++j) acc[i][j] = 0.f;

    for (int k0 = 0; k0 < K; k0 += KC) {
#pragma unroll
        for (int i = 0; i < 2; ++i) {
            int fid = t + 256 * i;
            int row = fid >> 3, kq = fid & 7;
            int gr = row0 + row; if (gr > NN - 1) gr = NN - 1;
            float4 v = *(const float4*)&X[(size_t)gr * K + k0 + kq * 4];
            xs[kq * 4 + 0][row] = v.x;
            xs[kq * 4 + 1][row] = v.y;
            xs[kq * 4 + 2][row] = v.z;
            xs[kq * 4 + 3][row] = v.w;
        }
#pragma unroll
        for (int i = 0; i < M / 32; ++i) {
            int fid = t + 256 * i;
            int m = fid >> 3, kq = fid & 7;
            float4 v = *(const float4*)&W[(size_t)m * K + k0 + kq * 4];
            ws[kq * 4 + 0][m] = v.x;
            ws[kq * 4 + 1][m] = v.y;
            ws[kq * 4 + 2][m] = v.z;
            ws[kq * 4 + 3][m] = v.w;
        }
        __syncthreads();
#pragma unroll
        for (int kk = 0; kk < KC; ++kk) {
            float4 wv = *(const float4*)&ws[kk][col4 * 4];
            float wa[4] = {wv.x, wv.y, wv.z, wv.w};
#pragma unroll
            for (int rq = 0; rq < RPT / 4; ++rq) {
                float4 xv = *(const float4*)&xs[kk][rbase + rq * 4];
                float xa[4] = {xv.x, xv.y, xv.z, xv.w};
#pragma unroll
                for (int rr = 0; rr < 4; ++rr)
#pragma unroll
                    for (int c = 0; c < 4; ++c)
                        acc[rq * 4 + rr][c] += xa[rr] * wa[c];
            }
        }
        __syncthreads();
    }
#pragma unroll
    for (int i = 0; i < RPT; ++i) {
        int gr = row0 + rbase + i;
        if (gr < NN) {
            float4 v = make_float4(acc[i][0], acc[i][1], acc[i][2], acc[i][3]);
            *(float4*)&H[(size_t)gr * M + col4 * 4] = v;
        }
    }
}

// ---------------- propagate: out[:, g*D+j] = relu(b[j] + sum_e norm*h[src]) ----------------
// v3: 8-wide predicated edge unroll -> 8 independent float4 gathers (128B) in flight
// per lane. Counters showed 4-wide was still latency-bound (VALU 17%, fabric 49%).

template <int D>
__global__ __launch_bounds__(256) void k_prop(const float* __restrict__ h,
                                              const int2* __restrict__ csr,
                                              const int* __restrict__ roff,
                                              const float* __restrict__ dinv,
                                              const float* __restrict__ bias,
                                              float* __restrict__ xout) {
    constexpr int TPN = D / 4;        // lanes per node (32 or 16)
    constexpr int NPB = 256 / TPN;    // nodes per block (8 or 16)
    constexpr int UW = 8;             // unroll width (gathers in flight per lane)
    int g = blockIdx.y;
    int node = blockIdx.x * NPB + threadIdx.x / TPN;
    int j4 = (threadIdx.x % TPN) * 4;
    if (node >= NN) return;
    const int2* ec = csr + (size_t)g * NE;
    int beg = roff[g * RP + node];
    int end = roff[g * RP + node + 1];
    float dv = dinv[g * NP + node];
    float sn = dv * dv;               // self-loop norm = dinv^2 * 1.0
    float4 hv = *(const float4*)&h[(size_t)node * D + j4];
    float4 acc = make_float4(sn * hv.x, sn * hv.y, sn * hv.z, sn * hv.w);
    for (int e = beg; e < end; e += UW) {
        int2 d[UW];
        float nrm[UW];
#pragma unroll
        for (int i = 0; i < UW; ++i) {
            bool valid = (e + i) < end;
            d[i] = ec[valid ? (e + i) : beg];
            nrm[i] = valid ? __int_as_float(d[i].y) : 0.f;
        }
        float4 hg[UW];
#pragma unroll
        for (int i = 0; i < UW; ++i)
            hg[i] = *(const float4*)&h[(size_t)d[i].x * D + j4];
#pragma unroll
        for (int i = 0; i < UW; ++i) {
            acc.x += nrm[i] * hg[i].x;
            acc.y += nrm[i] * hg[i].y;
            acc.z += nrm[i] * hg[i].z;
            acc.w += nrm[i] * hg[i].w;
        }
    }
    float4 bv = *(const float4*)&bias[j4];
    float4 r = make_float4(acc.x + bv.x, acc.y + bv.y, acc.z + bv.z, acc.w + bv.w);
    r.x = r.x > 0.f ? r.x : 0.f;
    r.y = r.y > 0.f ? r.y : 0.f;
    r.z = r.z > 0.f ? r.z : 0.f;
    r.w = r.w > 0.f ? r.w : 0.f;
    *(float4*)&xout[(size_t)node * (3 * D) + g * D + j4] = r;
}

// ---------------- final: y = x3 @ Wc^T + bc -> log_softmax ----------------

__global__ __launch_bounds__(256) void k_final(const float* __restrict__ x,
                                               const float* __restrict__ Wc,
                                               const float* __restrict__ bc,
                                               float* __restrict__ out) {
    __shared__ __align__(16) float wl[4 * 192];
    __shared__ float bl[4];
    for (int i = threadIdx.x; i < 4 * 192; i += 256) wl[i] = Wc[i];
    if (threadIdx.x < 4) bl[threadIdx.x] = bc[threadIdx.x];
    __syncthreads();
    int node = blockIdx.x * 256 + threadIdx.x;
    if (node >= NN) return;
    const float4* xr = (const float4*)(x + (size_t)node * 192);
    float a[4] = {bl[0], bl[1], bl[2], bl[3]};
#pragma unroll
    for (int q = 0; q < 48; ++q) {
        float4 xv = xr[q];
#pragma unroll
        for (int o = 0; o < 4; ++o) {
            float4 wv = *(const float4*)&wl[o * 192 + q * 4];
            a[o] += xv.x * wv.x + xv.y * wv.y + xv.z * wv.z + xv.w * wv.w;
        }
    }
    float m = fmaxf(fmaxf(a[0], a[1]), fmaxf(a[2], a[3]));
    float s = expf(a[0] - m) + expf(a[1] - m) + expf(a[2] - m) + expf(a[3] - m);
    float ls = logf(s);
    *(float4*)&out[(size_t)node * 4] =
        make_float4(a[0] - m - ls, a[1] - m - ls, a[2] - m - ls, a[3] - m - ls);
}

// ---------------- launch ----------------

extern "C" void kernel_launch(void* const* d_in, const int* in_sizes, int n_in,
                              void* d_out, int out_size, void* d_ws, size_t ws_size,
                              hipStream_t stream) {
    const float* x0 = (const float*)d_in[0];
    const int* e0 = (const int*)d_in[1];
    const int* e1 = (const int*)d_in[2];
    const int* e2 = (const int*)d_in[3];
    const float* w1 = (const float*)d_in[4];
    const float* w2 = (const float*)d_in[5];
    const float* W0 = (const float*)d_in[6];
    const float* W1 = (const float*)d_in[7];
    const float* W2 = (const float*)d_in[8];
    const float* b0 = (const float*)d_in[9];
    const float* b1 = (const float*)d_in[10];
    const float* b2 = (const float*)d_in[11];
    const float* Wc = (const float*)d_in[12];
    const float* bc = (const float*)d_in[13];
    float* out = (float*)d_out;

    char* wp = (char*)d_ws;
    auto alloc = [&](size_t bytes) -> void* {
        void* p = (void*)wp;
        wp += (bytes + 255) & ~(size_t)255;
        return p;
    };
    unsigned long long* combo = (unsigned long long*)alloc((size_t)3 * NP * 8);
    float*          dinv = (float*)alloc((size_t)3 * NP * 4);
    int*            roff = (int*)alloc((size_t)3 * RP * 4);
    unsigned short* rank = (unsigned short*)alloc((size_t)3 * NE * 2);
    int2*           csr  = (int2*)alloc((size_t)3 * NE * 8);
    float*          hbuf = (float*)alloc((size_t)NN * 128 * 4);
    float*          xA   = (float*)alloc((size_t)NN * 384 * 4);

    hipMemsetAsync(combo, 0, (size_t)3 * NP * 8, stream);
    k_count<<<dim3((NE + 255) / 256, 3), 256, 0, stream>>>(e0, e1, e2, w1, w2, combo, rank);
    k_dinv<<<(3 * NP + 255) / 256, 256, 0, stream>>>(combo, dinv);
    k_scan<<<3, 1024, 0, stream>>>(combo, roff);
    k_fill<<<dim3((NE + 255) / 256, 3), 256, 0, stream>>>(e0, e1, e2, w1, w2, dinv, roff, rank, csr);

    // layer 0: x[50000,128] -> h[50000,128] -> xA[50000,384]
    k_gemm<128, 128><<<(NN + 63) / 64, 256, 0, stream>>>(x0, W0, hbuf);
    k_prop<128><<<dim3((NN + 7) / 8, 3), 256, 0, stream>>>(hbuf, csr, roff, dinv, b0, xA);
    // layer 1
    k_gemm<384, 128><<<(NN + 63) / 64, 256, 0, stream>>>(xA, W1, hbuf);
    k_prop<128><<<dim3((NN + 7) / 8, 3), 256, 0, stream>>>(hbuf, csr, roff, dinv, b1, xA);
    // layer 2: -> d_out[:, :192]
    k_gemm<384, 64><<<(NN + 63) / 64, 256, 0, stream>>>(xA, W2, hbuf);
    k_prop<64><<<dim3((NN + 15) / 16, 3), 256, 0, stream>>>(hbuf, csr, roff, dinv, b2, out);
    // final: log_softmax(x3 @ Wc^T + bc) -> d_out[:, 192:]
    k_final<<<(NN + 255) / 256, 256, 0, stream>>>(out, Wc, bc, out + (size_t)NN * 192);
}

// Round 8
// 757.169 us; speedup vs baseline: 1.2801x; 1.2801x over previous
//
#include <hip/hip_runtime.h>
#include <hip/hip_bf16.h>

constexpr int NN = 50000;       // nodes
constexpr int NE = 800000;      // edges per graph
constexpr int NP = 50176;       // padded per-graph node stride
constexpr int RP = 50240;       // row-offset stride (>= NN+1)

__device__ __forceinline__ unsigned short bf16rne(float f) {
    unsigned int u = __float_as_uint(f);
    unsigned int r = (u + 0x7FFFu + ((u >> 16) & 1u)) >> 16;   // round-nearest-even
    return (unsigned short)r;
}
__device__ __forceinline__ float bf16tof(unsigned short s) {
    return __uint_as_float((unsigned int)s << 16);
}

// ---------------- CSR / norm build ----------------
// combo[node]: bits 44..63 = edge count, bits 0..43 = sum(w) in 2^-32 fixed point.
// One 64-bit atomic per edge; returned old count field = edge's rank in its dst row.

__global__ __launch_bounds__(256) void k_count(
    const int* __restrict__ e0, const int* __restrict__ e1, const int* __restrict__ e2,
    const float* __restrict__ w1, const float* __restrict__ w2,
    unsigned long long* __restrict__ combo, unsigned short* __restrict__ rank) {
    int g = blockIdx.y;
    int e = blockIdx.x * 256 + threadIdx.x;
    if (e >= NE) return;
    const int* ep = (g == 0) ? e0 : (g == 1) ? e1 : e2;
    float w = (g == 0) ? 1.0f : (g == 1) ? w1[e] : w2[e];
    int dst = ep[NE + e];
    unsigned long long wfix = (unsigned long long)llrint((double)w * 4294967296.0);
    unsigned long long old = atomicAdd(&combo[g * NP + dst], (1ULL << 44) | wfix);
    rank[(size_t)g * NE + e] = (unsigned short)(old >> 44);
}

__global__ __launch_bounds__(256) void k_dinv(const unsigned long long* __restrict__ combo,
                                              float* __restrict__ dinv) {
    int i = blockIdx.x * 256 + threadIdx.x;
    if (i >= 3 * NP) return;
    unsigned long long v = combo[i];
    double d = (double)(v & ((1ULL << 44) - 1)) * (1.0 / 4294967296.0) + 1.0;  // + self-loop
    dinv[i] = (float)(1.0 / sqrt(d));   // d >= 1 always
}

// one workgroup per graph: chunked sequential sums + Hillis-Steele scan of partials
__global__ __launch_bounds__(1024) void k_scan(const unsigned long long* __restrict__ combo,
                                               int* __restrict__ roff) {
    int g = blockIdx.x;
    const unsigned long long* c = combo + g * NP;
    int* r = roff + g * RP;
    int t = threadIdx.x;
    constexpr int CH = (NN + 1023) / 1024;  // 49
    int lo = t * CH;
    int hi = lo + CH < NN ? lo + CH : NN;
    int s = 0;
    for (int i = lo; i < hi; ++i) s += (int)(c[i] >> 44);
    __shared__ int part[1024];
    part[t] = s;
    __syncthreads();
    for (int off = 1; off < 1024; off <<= 1) {
        int v = (t >= off) ? part[t - off] : 0;
        __syncthreads();
        part[t] += v;
        __syncthreads();
    }
    int run = part[t] - s;  // exclusive base for this chunk
    for (int i = lo; i < hi; ++i) { r[i] = run; run += (int)(c[i] >> 44); }
    if (t == 1023) r[NN] = part[1023];
}

__global__ __launch_bounds__(256) void k_fill(
    const int* __restrict__ e0, const int* __restrict__ e1, const int* __restrict__ e2,
    const float* __restrict__ w1, const float* __restrict__ w2,
    const float* __restrict__ dinv, const int* __restrict__ roff,
    const unsigned short* __restrict__ rank, int2* __restrict__ csr) {
    int g = blockIdx.y;
    int e = blockIdx.x * 256 + threadIdx.x;
    if (e >= NE) return;
    const int* ep = (g == 0) ? e0 : (g == 1) ? e1 : e2;
    float w = (g == 0) ? 1.0f : (g == 1) ? w1[e] : w2[e];
    int src = ep[e];
    int dst = ep[NE + e];
    float nrm = dinv[g * NP + src] * w * dinv[g * NP + dst];
    int pos = roff[g * RP + dst] + (int)rank[(size_t)g * NE + e];
    csr[(size_t)g * NE + pos] = make_int2(src, __float_as_int(nrm));
}

// ---------------- fp32 tiled GEMM: H[N,M] = X[N,K] @ W[M,K]^T, bf16 output ----------------

template <int K, int M>
__global__ __launch_bounds__(256) void k_gemm(const float* __restrict__ X,
                                              const float* __restrict__ W,
                                              unsigned short* __restrict__ H) {
    constexpr int BM = 64, KC = 32;
    constexpr int CG = M / 4;      // col groups (32 or 16)
    constexpr int RG = 256 / CG;   // row groups (8 or 16)
    constexpr int RPT = BM / RG;   // rows per thread (8 or 4)
    __shared__ __align__(16) float xs[KC][68];      // [k][row], +4 pad
    __shared__ __align__(16) float ws[KC][M + 4];   // [k][m]
    int t = threadIdx.x;
    int row0 = blockIdx.x * BM;
    int col4 = t % CG;
    int rbase = (t / CG) * RPT;
    float acc[RPT][4];
#pragma unroll
    for (int i = 0; i < RPT; ++i)
#pragma unroll
        for (int j = 0; j < 4; ++j) acc[i][j] = 0.f;

    for (int k0 = 0; k0 < K; k0 += KC) {
#pragma unroll
        for (int i = 0; i < 2; ++i) {
            int fid = t + 256 * i;
            int row = fid >> 3, kq = fid & 7;
            int gr = row0 + row; if (gr > NN - 1) gr = NN - 1;
            float4 v = *(const float4*)&X[(size_t)gr * K + k0 + kq * 4];
            xs[kq * 4 + 0][row] = v.x;
            xs[kq * 4 + 1][row] = v.y;
            xs[kq * 4 + 2][row] = v.z;
            xs[kq * 4 + 3][row] = v.w;
        }
#pragma unroll
        for (int i = 0; i < M / 32; ++i) {
            int fid = t + 256 * i;
            int m = fid >> 3, kq = fid & 7;
            float4 v = *(const float4*)&W[(size_t)m * K + k0 + kq * 4];
            ws[kq * 4 + 0][m] = v.x;
            ws[kq * 4 + 1][m] = v.y;
            ws[kq * 4 + 2][m] = v.z;
            ws[kq * 4 + 3][m] = v.w;
        }
        __syncthreads();
#pragma unroll
        for (int kk = 0; kk < KC; ++kk) {
            float4 wv = *(const float4*)&ws[kk][col4 * 4];
            float wa[4] = {wv.x, wv.y, wv.z, wv.w};
#pragma unroll
            for (int rq = 0; rq < RPT / 4; ++rq) {
                float4 xv = *(const float4*)&xs[kk][rbase + rq * 4];
                float xa[4] = {xv.x, xv.y, xv.z, xv.w};
#pragma unroll
                for (int rr = 0; rr < 4; ++rr)
#pragma unroll
                    for (int c = 0; c < 4; ++c)
                        acc[rq * 4 + rr][c] += xa[rr] * wa[c];
            }
        }
        __syncthreads();
    }
#pragma unroll
    for (int i = 0; i < RPT; ++i) {
        int gr = row0 + rbase + i;
        if (gr < NN) {
            ushort4 v;
            v.x = bf16rne(acc[i][0]);
            v.y = bf16rne(acc[i][1]);
            v.z = bf16rne(acc[i][2]);
            v.w = bf16rne(acc[i][3]);
            *(ushort4*)&H[(size_t)gr * M + col4 * 4] = v;
        }
    }
}

// ---------------- propagate: out[:, g*D+j] = relu(b[j] + sum_e norm*h[src]) ----------------
// v4: h gathered as bf16 (halves L2-miss byte traffic — k_prop was throughput-bound at
// the TCC fetch path, 585 MB @ 3.4 TB/s; MLP-doubling was neutral). fp32 accumulate.

template <int D>
__global__ __launch_bounds__(256) void k_prop(const unsigned short* __restrict__ h,
                                              const int2* __restrict__ csr,
                                              const int* __restrict__ roff,
                                              const float* __restrict__ dinv,
                                              const float* __restrict__ bias,
                                              float* __restrict__ xout) {
    constexpr int TPN = D / 4;        // lanes per node (32 or 16)
    constexpr int NPB = 256 / TPN;    // nodes per block (8 or 16)
    constexpr int UW = 8;             // gathers in flight per lane
    int g = blockIdx.y;
    int node = blockIdx.x * NPB + threadIdx.x / TPN;
    int j4 = (threadIdx.x % TPN) * 4;
    if (node >= NN) return;
    const int2* ec = csr + (size_t)g * NE;
    int beg = roff[g * RP + node];
    int end = roff[g * RP + node + 1];
    float dv = dinv[g * NP + node];
    float sn = dv * dv;               // self-loop norm = dinv^2 * 1.0
    ushort4 hs = *(const ushort4*)&h[(size_t)node * D + j4];
    float4 acc = make_float4(sn * bf16tof(hs.x), sn * bf16tof(hs.y),
                             sn * bf16tof(hs.z), sn * bf16tof(hs.w));
    for (int e = beg; e < end; e += UW) {
        int2 d[UW];
        float nrm[UW];
#pragma unroll
        for (int i = 0; i < UW; ++i) {
            bool valid = (e + i) < end;
            d[i] = ec[valid ? (e + i) : beg];
            nrm[i] = valid ? __int_as_float(d[i].y) : 0.f;
        }
        ushort4 hg[UW];
#pragma unroll
        for (int i = 0; i < UW; ++i)
            hg[i] = *(const ushort4*)&h[(size_t)d[i].x * D + j4];
#pragma unroll
        for (int i = 0; i < UW; ++i) {
            acc.x += nrm[i] * bf16tof(hg[i].x);
            acc.y += nrm[i] * bf16tof(hg[i].y);
            acc.z += nrm[i] * bf16tof(hg[i].z);
            acc.w += nrm[i] * bf16tof(hg[i].w);
        }
    }
    float4 bv = *(const float4*)&bias[j4];
    float4 r = make_float4(acc.x + bv.x, acc.y + bv.y, acc.z + bv.z, acc.w + bv.w);
    r.x = r.x > 0.f ? r.x : 0.f;
    r.y = r.y > 0.f ? r.y : 0.f;
    r.z = r.z > 0.f ? r.z : 0.f;
    r.w = r.w > 0.f ? r.w : 0.f;
    *(float4*)&xout[(size_t)node * (3 * D) + g * D + j4] = r;
}

// ---------------- final: y = x3 @ Wc^T + bc -> log_softmax ----------------

__global__ __launch_bounds__(256) void k_final(const float* __restrict__ x,
                                               const float* __restrict__ Wc,
                                               const float* __restrict__ bc,
                                               float* __restrict__ out) {
    __shared__ __align__(16) float wl[4 * 192];
    __shared__ float bl[4];
    for (int i = threadIdx.x; i < 4 * 192; i += 256) wl[i] = Wc[i];
    if (threadIdx.x < 4) bl[threadIdx.x] = bc[threadIdx.x];
    __syncthreads();
    int node = blockIdx.x * 256 + threadIdx.x;
    if (node >= NN) return;
    const float4* xr = (const float4*)(x + (size_t)node * 192);
    float a[4] = {bl[0], bl[1], bl[2], bl[3]};
#pragma unroll
    for (int q = 0; q < 48; ++q) {
        float4 xv = xr[q];
#pragma unroll
        for (int o = 0; o < 4; ++o) {
            float4 wv = *(const float4*)&wl[o * 192 + q * 4];
            a[o] += xv.x * wv.x + xv.y * wv.y + xv.z * wv.z + xv.w * wv.w;
        }
    }
    float m = fmaxf(fmaxf(a[0], a[1]), fmaxf(a[2], a[3]));
    float s = expf(a[0] - m) + expf(a[1] - m) + expf(a[2] - m) + expf(a[3] - m);
    float ls = logf(s);
    *(float4*)&out[(size_t)node * 4] =
        make_float4(a[0] - m - ls, a[1] - m - ls, a[2] - m - ls, a[3] - m - ls);
}

// ---------------- launch ----------------

extern "C" void kernel_launch(void* const* d_in, const int* in_sizes, int n_in,
                              void* d_out, int out_size, void* d_ws, size_t ws_size,
                              hipStream_t stream) {
    const float* x0 = (const float*)d_in[0];
    const int* e0 = (const int*)d_in[1];
    const int* e1 = (const int*)d_in[2];
    const int* e2 = (const int*)d_in[3];
    const float* w1 = (const float*)d_in[4];
    const float* w2 = (const float*)d_in[5];
    const float* W0 = (const float*)d_in[6];
    const float* W1 = (const float*)d_in[7];
    const float* W2 = (const float*)d_in[8];
    const float* b0 = (const float*)d_in[9];
    const float* b1 = (const float*)d_in[10];
    const float* b2 = (const float*)d_in[11];
    const float* Wc = (const float*)d_in[12];
    const float* bc = (const float*)d_in[13];
    float* out = (float*)d_out;

    char* wp = (char*)d_ws;
    auto alloc = [&](size_t bytes) -> void* {
        void* p = (void*)wp;
        wp += (bytes + 255) & ~(size_t)255;
        return p;
    };
    unsigned long long* combo = (unsigned long long*)alloc((size_t)3 * NP * 8);
    float*          dinv = (float*)alloc((size_t)3 * NP * 4);
    int*            roff = (int*)alloc((size_t)3 * RP * 4);
    unsigned short* rank = (unsigned short*)alloc((size_t)3 * NE * 2);
    int2*           csr  = (int2*)alloc((size_t)3 * NE * 8);
    unsigned short* hbuf = (unsigned short*)alloc((size_t)NN * 128 * 2);   // bf16 h
    float*          xA   = (float*)alloc((size_t)NN * 384 * 4);

    hipMemsetAsync(combo, 0, (size_t)3 * NP * 8, stream);
    k_count<<<dim3((NE + 255) / 256, 3), 256, 0, stream>>>(e0, e1, e2, w1, w2, combo, rank);
    k_dinv<<<(3 * NP + 255) / 256, 256, 0, stream>>>(combo, dinv);
    k_scan<<<3, 1024, 0, stream>>>(combo, roff);
    k_fill<<<dim3((NE + 255) / 256, 3), 256, 0, stream>>>(e0, e1, e2, w1, w2, dinv, roff, rank, csr);

    // layer 0: x[50000,128] -> h[50000,128] (bf16) -> xA[50000,384]
    k_gemm<128, 128><<<(NN + 63) / 64, 256, 0, stream>>>(x0, W0, hbuf);
    k_prop<128><<<dim3((NN + 7) / 8, 3), 256, 0, stream>>>(hbuf, csr, roff, dinv, b0, xA);
    // layer 1
    k_gemm<384, 128><<<(NN + 63) / 64, 256, 0, stream>>>(xA, W1, hbuf);
    k_prop<128><<<dim3((NN + 7) / 8, 3), 256, 0, stream>>>(hbuf, csr, roff, dinv, b1, xA);
    // layer 2: -> d_out[:, :192]
    k_gemm<384, 64><<<(NN + 63) / 64, 256, 0, stream>>>(xA, W2, hbuf);
    k_prop<64><<<dim3((NN + 15) / 16, 3), 256, 0, stream>>>(hbuf, csr, roff, dinv, b2, out);
    // final: log_softmax(x3 @ Wc^T + bc) -> d_out[:, 192:]
    k_final<<<(NN + 255) / 256, 256, 0, stream>>>(out, Wc, bc, out + (size_t)NN * 192);
}